// Round 3
// baseline (295.052 us; speedup 1.0000x reference)
//
#include <hip/hip_runtime.h>

#define HID 768
#define NHEAD 12
#define HD 64
#define SEQ 2048
#define BATCH 2
#define PH (BATCH * NHEAD * SEQ * HD)   // 3,145,728 elements per Q/K/V plane

typedef __attribute__((ext_vector_type(8))) short bf16x8;
typedef __attribute__((ext_vector_type(4))) short bf16x4;
typedef __attribute__((ext_vector_type(4))) float f32x4;

static __device__ __forceinline__ short f2b(float f) {
  unsigned int u = __builtin_bit_cast(unsigned int, f);
  unsigned int r = (u + 0x7fffu + ((u >> 16) & 1u)) >> 16;
  return (short)(unsigned short)r;
}

// ---------------------------------------------------------------------------
// Kernel 1: fused QKV projection.  X[4096,768] @ {Wq,Wk,Wv}[768,768] + bias.
// Grid (36, 64), block 256 (4 waves). Wave tile: 64 M x 16 N.
// Output: bf16 [B][H][S][64] planes in workspace.
// ---------------------------------------------------------------------------
__global__ __launch_bounds__(256) void qkv_proj(
    const float* __restrict__ X,
    const float* __restrict__ Wq, const float* __restrict__ bq,
    const float* __restrict__ Wk, const float* __restrict__ bk,
    const float* __restrict__ Wv, const float* __restrict__ bv,
    short* __restrict__ Qb, short* __restrict__ Kb, short* __restrict__ Vb)
{
  const int tid = threadIdx.x;
  const int w  = tid >> 6;      // wave 0..3
  const int l  = tid & 63;
  const int lr = l & 15;
  const int g  = l >> 4;        // 0..3
  const int bx = blockIdx.x;    // 0..35 : n-chunk of 64 (12 per matrix)
  const int by = blockIdx.y;    // 0..63 : m-chunk of 64
  const int mat = bx / 12;      // 0=Q 1=K 2=V
  const int h   = bx - mat * 12;
  const float* __restrict__ W    = (mat == 0) ? Wq : (mat == 1 ? Wk : Wv);
  const float* __restrict__ bias = (mat == 0) ? bq : (mat == 1 ? bk : bv);
  short* __restrict__ Out        = (mat == 0) ? Qb : (mat == 1 ? Kb : Vb);

  const int colb = h * 64 + w * 16;   // W column base for this wave
  const int col  = colb + lr;         // this lane's W column
  const int m0   = by * 64;
  const int b    = m0 >> 11;          // m0 / 2048

  f32x4 acc[4];
#pragma unroll
  for (int mt = 0; mt < 4; ++mt) acc[mt] = (f32x4){0.f, 0.f, 0.f, 0.f};

  for (int kk = 0; kk < HID; kk += 32) {
    const int krow = kk + 8 * g;
    // B-frag: W[krow+i][col], i=0..7 (k on 8g+i, n on lane&15)
    bf16x8 bf;
#pragma unroll
    for (int i = 0; i < 8; ++i) bf[i] = f2b(W[(krow + i) * HID + col]);
#pragma unroll
    for (int mt = 0; mt < 4; ++mt) {
      const float* xp = X + (size_t)(m0 + 16 * mt + lr) * HID + krow;
      f32x4 x0 = *(const f32x4*)xp;
      f32x4 x1 = *(const f32x4*)(xp + 4);
      bf16x8 af;
      af[0] = f2b(x0[0]); af[1] = f2b(x0[1]); af[2] = f2b(x0[2]); af[3] = f2b(x0[3]);
      af[4] = f2b(x1[0]); af[5] = f2b(x1[1]); af[6] = f2b(x1[2]); af[7] = f2b(x1[3]);
      acc[mt] = __builtin_amdgcn_mfma_f32_16x16x32_bf16(af, bf, acc[mt], 0, 0, 0);
    }
  }

  const float bias_v = bias[col];
  const int d = w * 16 + lr;
  short* ob = Out + (size_t)(b * NHEAD + h) * SEQ * HD;
#pragma unroll
  for (int mt = 0; mt < 4; ++mt) {
#pragma unroll
    for (int r = 0; r < 4; ++r) {
      const int m = m0 + 16 * mt + 4 * g + r;     // D row = 4g + r
      const int s = m & (SEQ - 1);
      ob[(size_t)s * HD + d] = f2b(acc[mt][r] + bias_v);
    }
  }
}

// ---------------------------------------------------------------------------
// Kernel 2: flash attention. Grid (32, 24), block 256 (4 waves).
// Each wave: 16 q-rows; block iterates kv-tiles of 32 in lockstep,
// staging K (linear) and V (transposed) in LDS.
// S^T = K * Q^T  ->  lane holds scores for q = lane&15 (lane-local row).
// O^T += V^T * P^T, P routed through small per-wave LDS tile.
// ---------------------------------------------------------------------------
__global__ __launch_bounds__(256) void attn_fwd(
    const short* __restrict__ Qb, const short* __restrict__ Kb,
    const short* __restrict__ Vb, const float* __restrict__ mask,
    float* __restrict__ out)
{
  __shared__ __align__(16) short K_lds[32][72];     // 144B rows (odd x16B: conflict-free b128)
  __shared__ __align__(16) short VT_lds[64][40];    // V transposed: [d][kv], 80B rows
  __shared__ __align__(16) short P_lds[4][16][40];  // per-wave P: [q][kv], 80B rows

  const int tid = threadIdx.x;
  const int w   = tid >> 6;
  const int l   = tid & 63;
  const int lr  = l & 15;
  const int g   = l >> 4;
  const int qblk = blockIdx.x;   // 0..31
  const int bh   = blockIdx.y;   // 0..23
  const int b    = bh / 12;
  const int h    = bh - b * 12;
  const int q0   = qblk * 64 + w * 16;

  const short* __restrict__ Qh = Qb + (size_t)bh * SEQ * HD;
  const short* __restrict__ Kh = Kb + (size_t)bh * SEQ * HD;
  const short* __restrict__ Vh = Vb + (size_t)bh * SEQ * HD;
  const float* __restrict__ mb = mask + (size_t)b * SEQ;

  // Hoisted Q fragments (B-operand of S^T): Q[q0+lr][kk + 8g + i]
  const bf16x8 qf0 = *(const bf16x8*)(Qh + (size_t)(q0 + lr) * HD + 8 * g);
  const bf16x8 qf1 = *(const bf16x8*)(Qh + (size_t)(q0 + lr) * HD + 32 + 8 * g);

  f32x4 ot[4];
#pragma unroll
  for (int d0 = 0; d0 < 4; ++d0) ot[d0] = (f32x4){0.f, 0.f, 0.f, 0.f};
  float m_run = -INFINITY;
  float l_run = 0.f;

  // staging indices
  const int srow = tid >> 3;          // 0..31 (K row)
  const int sc8  = (tid & 7) * 8;     // K col block
  const int vdr  = tid & 63;          // 0..63 (V d-row in VT)
  const int vkh  = tid >> 6;          // 0..3  (V kv block of 8)

  for (int kv0 = 0; kv0 < SEQ; kv0 += 32) {
    __syncthreads();
    // stage K tile [32][64] linearly
    *(bf16x8*)&K_lds[srow][sc8] =
        *(const bf16x8*)(Kh + (size_t)(kv0 + srow) * HD + sc8);
    // stage V tile transposed: VT[d][kv] (coalesced 2B loads, b128 LDS write)
    bf16x8 vv;
#pragma unroll
    for (int i = 0; i < 8; ++i)
      vv[i] = Vh[(size_t)(kv0 + 8 * vkh + i) * HD + vdr];
    *(bf16x8*)&VT_lds[vdr][8 * vkh] = vv;
    __syncthreads();

    // S^T = K * Q^T  (two 16-kv subtiles, K-dim 64 via 2 chained MFMAs)
    f32x4 st[2];
#pragma unroll
    for (int s = 0; s < 2; ++s) {
      bf16x8 ka0 = *(const bf16x8*)&K_lds[16 * s + lr][8 * g];
      bf16x8 ka1 = *(const bf16x8*)&K_lds[16 * s + lr][32 + 8 * g];
      f32x4 z = (f32x4){0.f, 0.f, 0.f, 0.f};
      z = __builtin_amdgcn_mfma_f32_16x16x32_bf16(ka0, qf0, z, 0, 0, 0);
      z = __builtin_amdgcn_mfma_f32_16x16x32_bf16(ka1, qf1, z, 0, 0, 0);
      st[s] = z;
    }

    // scores + online softmax; lane owns q = lr; kv' = 16s + 4g + r
    float p[8];
    float tm = -INFINITY;
#pragma unroll
    for (int s = 0; s < 2; ++s) {
      f32x4 mv = *(const f32x4*)&mb[kv0 + 16 * s + 4 * g];
#pragma unroll
      for (int r = 0; r < 4; ++r) {
        float sc = st[s][r] * 0.125f + mv[r];
        p[4 * s + r] = sc;
        tm = fmaxf(tm, sc);
      }
    }
    tm = fmaxf(tm, __shfl_xor(tm, 16, 64));
    tm = fmaxf(tm, __shfl_xor(tm, 32, 64));
    const float m_new = fmaxf(m_run, tm);
    const float alpha = __expf(m_run - m_new);   // first iter: exp(-inf)=0
    float tsum = 0.f;
#pragma unroll
    for (int i = 0; i < 8; ++i) { p[i] = __expf(p[i] - m_new); tsum += p[i]; }
    tsum += __shfl_xor(tsum, 16, 64);
    tsum += __shfl_xor(tsum, 32, 64);
    l_run = l_run * alpha + tsum;
    m_run = m_new;
#pragma unroll
    for (int d0 = 0; d0 < 4; ++d0) ot[d0] *= alpha;

    // route P through per-wave LDS to fix 4-row->8-row fragment granularity
    bf16x4 pk0 = (bf16x4){f2b(p[0]), f2b(p[1]), f2b(p[2]), f2b(p[3])};
    bf16x4 pk1 = (bf16x4){f2b(p[4]), f2b(p[5]), f2b(p[6]), f2b(p[7])};
    *(bf16x4*)&P_lds[w][lr][4 * g]      = pk0;
    *(bf16x4*)&P_lds[w][lr][16 + 4 * g] = pk1;
    __syncthreads();   // also guarantees P write->read ordering

    // O^T += V^T * P^T  (one MFMA per 16-d block, K-dim 32)
    const bf16x8 pb = *(const bf16x8*)&P_lds[w][lr][8 * g];
#pragma unroll
    for (int d0 = 0; d0 < 4; ++d0) {
      bf16x8 va = *(const bf16x8*)&VT_lds[16 * d0 + lr][8 * g];
      ot[d0] = __builtin_amdgcn_mfma_f32_16x16x32_bf16(va, pb, ot[d0], 0, 0, 0);
    }
  }

  const float inv = 1.f / l_run;
  float* ob = out + (size_t)(b * SEQ + q0 + lr) * HID + h * HD;
#pragma unroll
  for (int d0 = 0; d0 < 4; ++d0) {
    f32x4 o = ot[d0] * inv;   // O[q][d], d = 16*d0 + 4g + r
    *(f32x4*)&ob[16 * d0 + 4 * g] = o;
  }
}

// ---------------------------------------------------------------------------
extern "C" void kernel_launch(void* const* d_in, const int* in_sizes, int n_in,
                              void* d_out, int out_size, void* d_ws, size_t ws_size,
                              hipStream_t stream) {
  const float* X    = (const float*)d_in[0];
  const float* mask = (const float*)d_in[1];
  const float* Wq   = (const float*)d_in[2];
  const float* bq   = (const float*)d_in[3];
  const float* Wk   = (const float*)d_in[4];
  const float* bk   = (const float*)d_in[5];
  const float* Wv   = (const float*)d_in[6];
  const float* bv   = (const float*)d_in[7];
  float* out = (float*)d_out;

  short* Qb = (short*)d_ws;
  short* Kb = Qb + PH;
  short* Vb = Kb + PH;

  qkv_proj<<<dim3(36, 64), 256, 0, stream>>>(X, Wq, bq, Wk, bk, Wv, bv, Qb, Kb, Vb);
  attn_fwd<<<dim3(32, 24), 256, 0, stream>>>(Qb, Kb, Vb, mask, out);
}

// Round 4
// 169.745 us; speedup vs baseline: 1.7382x; 1.7382x over previous
//
#include <hip/hip_runtime.h>

#define HID 768
#define NHEAD 12
#define HD 64
#define SEQ 2048
#define BATCH 2
#define PH (BATCH * NHEAD * SEQ * HD)   // 3,145,728 elements per Q/K/V plane
#define XEL (BATCH * SEQ * HID)         // 3,145,728 X elements
#define NTOT (3 * HID)                  // 2304 fused N

typedef __attribute__((ext_vector_type(8))) short bf16x8;
typedef __attribute__((ext_vector_type(4))) short bf16x4;
typedef __attribute__((ext_vector_type(4))) float f32x4;

static __device__ __forceinline__ short f2b(float f) {
  unsigned int u = __builtin_bit_cast(unsigned int, f);
  unsigned int r = (u + 0x7fffu + ((u >> 16) & 1u)) >> 16;
  return (short)(unsigned short)r;
}

// ---------------------------------------------------------------------------
// Prep: blocks [0,768)   : X f32 -> Xb bf16 (4096 elems/block)
//       blocks [768,1200): W transpose+convert -> Wt[n][k] bf16, 64x64 tiles
// ---------------------------------------------------------------------------
__global__ __launch_bounds__(256) void prep(
    const float* __restrict__ X,
    const float* __restrict__ Wq, const float* __restrict__ Wk,
    const float* __restrict__ Wv,
    short* __restrict__ Xb, short* __restrict__ Wt)
{
  __shared__ short T[64][65];
  const int t = threadIdx.x;
  const int blk = blockIdx.x;
  if (blk < 768) {
    const size_t base = (size_t)blk * 4096 + t * 16;
    f32x4 a0 = *(const f32x4*)(X + base);
    f32x4 a1 = *(const f32x4*)(X + base + 4);
    f32x4 a2 = *(const f32x4*)(X + base + 8);
    f32x4 a3 = *(const f32x4*)(X + base + 12);
    bf16x8 o0, o1;
#pragma unroll
    for (int i = 0; i < 4; ++i) {
      o0[i] = f2b(a0[i]); o0[4 + i] = f2b(a1[i]);
      o1[i] = f2b(a2[i]); o1[4 + i] = f2b(a3[i]);
    }
    *(bf16x8*)(Xb + base) = o0;
    *(bf16x8*)(Xb + base + 8) = o1;
  } else {
    const int wb   = blk - 768;       // 0..431
    const int mat  = wb / 144;        // 0=Q 1=K 2=V
    const int tile = wb - mat * 144;  // 12x12 tiles of 64x64
    const int r0 = (tile / 12) * 64;  // k-row base
    const int c0 = (tile % 12) * 64;  // col base
    const float* __restrict__ W = (mat == 0) ? Wq : (mat == 1 ? Wk : Wv);
    // load 64x64 f32 tile coalesced, convert to bf16 in LDS
#pragma unroll
    for (int i = 0; i < 4; ++i) {
      const int r = (t >> 4) + 16 * i;
      const int c = (t & 15) * 4;
      f32x4 v = *(const f32x4*)(W + (size_t)(r0 + r) * HID + c0 + c);
      T[r][c + 0] = f2b(v[0]); T[r][c + 1] = f2b(v[1]);
      T[r][c + 2] = f2b(v[2]); T[r][c + 3] = f2b(v[3]);
    }
    __syncthreads();
    // write transposed rows: Wt[mat*768 + c0+cr][r0 + ck + j] = T[ck+j][cr]
    const int cr = t >> 2;
    const int ck = (t & 3) * 16;
    bf16x8 u0, u1;
#pragma unroll
    for (int j = 0; j < 8; ++j) { u0[j] = T[ck + j][cr]; u1[j] = T[ck + 8 + j][cr]; }
    short* orow = Wt + (size_t)(mat * HID + c0 + cr) * HID + r0 + ck;
    *(bf16x8*)orow = u0;
    *(bf16x8*)(orow + 8) = u1;
  }
}

// ---------------------------------------------------------------------------
// Fused QKV GEMM: Xb[4096,768] @ Wt^T -> Q/K/V bf16 planes [B][H][S][64].
// Grid (18, 32), block 256 (4 waves). Block tile 128x128, wave tile 64x64.
// Per k-step: 8 contiguous 16B loads + 16 MFMA.
// ---------------------------------------------------------------------------
__global__ __launch_bounds__(256) void qkv_gemm(
    const short* __restrict__ Xb, const short* __restrict__ Wt,
    const float* __restrict__ bq, const float* __restrict__ bk,
    const float* __restrict__ bv,
    short* __restrict__ Qb, short* __restrict__ Kb, short* __restrict__ Vb)
{
  const int tid = threadIdx.x;
  const int w  = tid >> 6;
  const int l  = tid & 63;
  const int lr = l & 15;
  const int g  = l >> 4;
  const int wm = w >> 1;
  const int wn = w & 1;
  const int m0 = blockIdx.y * 128 + wm * 64;
  const int n0 = blockIdx.x * 128 + wn * 64;

  const short* __restrict__ Ap = Xb + (size_t)(m0 + lr) * HID + 8 * g;
  const short* __restrict__ Bp = Wt + (size_t)(n0 + lr) * HID + 8 * g;

  f32x4 acc[4][4];
#pragma unroll
  for (int mi = 0; mi < 4; ++mi)
#pragma unroll
    for (int ni = 0; ni < 4; ++ni) acc[mi][ni] = (f32x4){0.f, 0.f, 0.f, 0.f};

  for (int k = 0; k < HID; k += 32) {
    bf16x8 a[4], b[4];
#pragma unroll
    for (int i = 0; i < 4; ++i) {
      a[i] = *(const bf16x8*)(Ap + (size_t)(16 * i) * HID + k);
      b[i] = *(const bf16x8*)(Bp + (size_t)(16 * i) * HID + k);
    }
#pragma unroll
    for (int mi = 0; mi < 4; ++mi)
#pragma unroll
      for (int ni = 0; ni < 4; ++ni)
        acc[mi][ni] = __builtin_amdgcn_mfma_f32_16x16x32_bf16(a[mi], b[ni], acc[mi][ni], 0, 0, 0);
  }

  // epilogue: bias + scatter into [B][H][S][64] bf16 planes
  const int mat  = n0 / HID;           // block-uniform (64 | 768)
  const int colb = n0 - mat * HID;
  const float* __restrict__ bias = (mat == 0) ? bq : (mat == 1 ? bk : bv);
  short* __restrict__ Out        = (mat == 0) ? Qb : (mat == 1 ? Kb : Vb);

#pragma unroll
  for (int ni = 0; ni < 4; ++ni) {
    const int col = colb + 16 * ni + lr;   // 0..767
    const int h = col >> 6, d = col & 63;
    const float bias_v = bias[col];
#pragma unroll
    for (int mi = 0; mi < 4; ++mi) {
      const int mbase = m0 + 16 * mi + 4 * g;
#pragma unroll
      for (int r = 0; r < 4; ++r) {
        const int m = mbase + r;
        const int bb = m >> 11;
        const int s  = m & (SEQ - 1);
        Out[((size_t)(bb * NHEAD + h) * SEQ + s) * HD + d] = f2b(acc[mi][ni][r] + bias_v);
      }
    }
  }
}

// ---------------------------------------------------------------------------
// Kernel 2: flash attention (unchanged from round 0 — verified PASS).
// ---------------------------------------------------------------------------
__global__ __launch_bounds__(256) void attn_fwd(
    const short* __restrict__ Qb, const short* __restrict__ Kb,
    const short* __restrict__ Vb, const float* __restrict__ mask,
    float* __restrict__ out)
{
  __shared__ __align__(16) short K_lds[32][72];
  __shared__ __align__(16) short VT_lds[64][40];
  __shared__ __align__(16) short P_lds[4][16][40];

  const int tid = threadIdx.x;
  const int w   = tid >> 6;
  const int l   = tid & 63;
  const int lr  = l & 15;
  const int g   = l >> 4;
  const int qblk = blockIdx.x;
  const int bh   = blockIdx.y;
  const int b    = bh / 12;
  const int h    = bh - b * 12;
  const int q0   = qblk * 64 + w * 16;

  const short* __restrict__ Qh = Qb + (size_t)bh * SEQ * HD;
  const short* __restrict__ Kh = Kb + (size_t)bh * SEQ * HD;
  const short* __restrict__ Vh = Vb + (size_t)bh * SEQ * HD;
  const float* __restrict__ mb = mask + (size_t)b * SEQ;

  const bf16x8 qf0 = *(const bf16x8*)(Qh + (size_t)(q0 + lr) * HD + 8 * g);
  const bf16x8 qf1 = *(const bf16x8*)(Qh + (size_t)(q0 + lr) * HD + 32 + 8 * g);

  f32x4 ot[4];
#pragma unroll
  for (int d0 = 0; d0 < 4; ++d0) ot[d0] = (f32x4){0.f, 0.f, 0.f, 0.f};
  float m_run = -INFINITY;
  float l_run = 0.f;

  const int srow = tid >> 3;
  const int sc8  = (tid & 7) * 8;
  const int vdr  = tid & 63;
  const int vkh  = tid >> 6;

  for (int kv0 = 0; kv0 < SEQ; kv0 += 32) {
    __syncthreads();
    *(bf16x8*)&K_lds[srow][sc8] =
        *(const bf16x8*)(Kh + (size_t)(kv0 + srow) * HD + sc8);
    bf16x8 vv;
#pragma unroll
    for (int i = 0; i < 8; ++i)
      vv[i] = Vh[(size_t)(kv0 + 8 * vkh + i) * HD + vdr];
    *(bf16x8*)&VT_lds[vdr][8 * vkh] = vv;
    __syncthreads();

    f32x4 st[2];
#pragma unroll
    for (int s = 0; s < 2; ++s) {
      bf16x8 ka0 = *(const bf16x8*)&K_lds[16 * s + lr][8 * g];
      bf16x8 ka1 = *(const bf16x8*)&K_lds[16 * s + lr][32 + 8 * g];
      f32x4 z = (f32x4){0.f, 0.f, 0.f, 0.f};
      z = __builtin_amdgcn_mfma_f32_16x16x32_bf16(ka0, qf0, z, 0, 0, 0);
      z = __builtin_amdgcn_mfma_f32_16x16x32_bf16(ka1, qf1, z, 0, 0, 0);
      st[s] = z;
    }

    float p[8];
    float tm = -INFINITY;
#pragma unroll
    for (int s = 0; s < 2; ++s) {
      f32x4 mv = *(const f32x4*)&mb[kv0 + 16 * s + 4 * g];
#pragma unroll
      for (int r = 0; r < 4; ++r) {
        float sc = st[s][r] * 0.125f + mv[r];
        p[4 * s + r] = sc;
        tm = fmaxf(tm, sc);
      }
    }
    tm = fmaxf(tm, __shfl_xor(tm, 16, 64));
    tm = fmaxf(tm, __shfl_xor(tm, 32, 64));
    const float m_new = fmaxf(m_run, tm);
    const float alpha = __expf(m_run - m_new);
    float tsum = 0.f;
#pragma unroll
    for (int i = 0; i < 8; ++i) { p[i] = __expf(p[i] - m_new); tsum += p[i]; }
    tsum += __shfl_xor(tsum, 16, 64);
    tsum += __shfl_xor(tsum, 32, 64);
    l_run = l_run * alpha + tsum;
    m_run = m_new;
#pragma unroll
    for (int d0 = 0; d0 < 4; ++d0) ot[d0] *= alpha;

    bf16x4 pk0 = (bf16x4){f2b(p[0]), f2b(p[1]), f2b(p[2]), f2b(p[3])};
    bf16x4 pk1 = (bf16x4){f2b(p[4]), f2b(p[5]), f2b(p[6]), f2b(p[7])};
    *(bf16x4*)&P_lds[w][lr][4 * g]      = pk0;
    *(bf16x4*)&P_lds[w][lr][16 + 4 * g] = pk1;
    __syncthreads();

    const bf16x8 pb = *(const bf16x8*)&P_lds[w][lr][8 * g];
#pragma unroll
    for (int d0 = 0; d0 < 4; ++d0) {
      bf16x8 va = *(const bf16x8*)&VT_lds[16 * d0 + lr][8 * g];
      ot[d0] = __builtin_amdgcn_mfma_f32_16x16x32_bf16(va, pb, ot[d0], 0, 0, 0);
    }
  }

  const float inv = 1.f / l_run;
  float* ob = out + (size_t)(b * SEQ + q0 + lr) * HID + h * HD;
#pragma unroll
  for (int d0 = 0; d0 < 4; ++d0) {
    f32x4 o = ot[d0] * inv;
    *(f32x4*)&ob[16 * d0 + 4 * g] = o;
  }
}

// ---------------------------------------------------------------------------
extern "C" void kernel_launch(void* const* d_in, const int* in_sizes, int n_in,
                              void* d_out, int out_size, void* d_ws, size_t ws_size,
                              hipStream_t stream) {
  const float* X    = (const float*)d_in[0];
  const float* mask = (const float*)d_in[1];
  const float* Wq   = (const float*)d_in[2];
  const float* bq   = (const float*)d_in[3];
  const float* Wk   = (const float*)d_in[4];
  const float* bk   = (const float*)d_in[5];
  const float* Wv   = (const float*)d_in[6];
  const float* bv   = (const float*)d_in[7];
  float* out = (float*)d_out;

  short* Qb = (short*)d_ws;
  short* Kb = Qb + PH;
  short* Vb = Kb + PH;
  short* Xb = Vb + PH;
  short* Wt = Xb + XEL;   // [2304][768] bf16

  prep<<<dim3(768 + 432), 256, 0, stream>>>(X, Wq, Wk, Wv, Xb, Wt);
  qkv_gemm<<<dim3(18, 32), 256, 0, stream>>>(Xb, Wt, bq, bk, bv, Qb, Kb, Vb);
  attn_fwd<<<dim3(32, 24), 256, 0, stream>>>(Qb, Kb, Vb, mask, out);
}

// Round 5
// 150.439 us; speedup vs baseline: 1.9613x; 1.1283x over previous
//
#include <hip/hip_runtime.h>

#define HID 768
#define NHEAD 12
#define HD 64
#define SEQ 2048
#define BATCH 2
#define PH (BATCH * NHEAD * SEQ * HD)   // 3,145,728 elements per Q/K/V plane
#define XEL (BATCH * SEQ * HID)
#define LOG2E 1.4426950408889634f
#define C1 (0.125f * LOG2E)             // QK scale folded with log2e

typedef __attribute__((ext_vector_type(8))) short bf16x8;
typedef __attribute__((ext_vector_type(4))) short bf16x4;
typedef __attribute__((ext_vector_type(4))) float f32x4;

static __device__ __forceinline__ short f2b(float f) {
  unsigned int u = __builtin_bit_cast(unsigned int, f);
  unsigned int r = (u + 0x7fffu + ((u >> 16) & 1u)) >> 16;
  return (short)(unsigned short)r;
}

// ---------------------------------------------------------------------------
// Prep: [0,768)     : X f32 -> Xb bf16
//       [768,1200)  : W transpose+convert -> Wt[n][k] bf16
//       1200        : mask2 = mask * log2e
// ---------------------------------------------------------------------------
__global__ __launch_bounds__(256) void prep(
    const float* __restrict__ X,
    const float* __restrict__ Wq, const float* __restrict__ Wk,
    const float* __restrict__ Wv, const float* __restrict__ mask,
    short* __restrict__ Xb, short* __restrict__ Wt, float* __restrict__ mask2)
{
  __shared__ short T[64][65];
  const int t = threadIdx.x;
  const int blk = blockIdx.x;
  if (blk < 768) {
    const size_t base = (size_t)blk * 4096 + t * 16;
    f32x4 a0 = *(const f32x4*)(X + base);
    f32x4 a1 = *(const f32x4*)(X + base + 4);
    f32x4 a2 = *(const f32x4*)(X + base + 8);
    f32x4 a3 = *(const f32x4*)(X + base + 12);
    bf16x8 o0, o1;
#pragma unroll
    for (int i = 0; i < 4; ++i) {
      o0[i] = f2b(a0[i]); o0[4 + i] = f2b(a1[i]);
      o1[i] = f2b(a2[i]); o1[4 + i] = f2b(a3[i]);
    }
    *(bf16x8*)(Xb + base) = o0;
    *(bf16x8*)(Xb + base + 8) = o1;
  } else if (blk < 1200) {
    const int wb   = blk - 768;
    const int mat  = wb / 144;
    const int tile = wb - mat * 144;
    const int r0 = (tile / 12) * 64;
    const int c0 = (tile % 12) * 64;
    const float* __restrict__ W = (mat == 0) ? Wq : (mat == 1 ? Wk : Wv);
#pragma unroll
    for (int i = 0; i < 4; ++i) {
      const int r = (t >> 4) + 16 * i;
      const int c = (t & 15) * 4;
      f32x4 v = *(const f32x4*)(W + (size_t)(r0 + r) * HID + c0 + c);
      T[r][c + 0] = f2b(v[0]); T[r][c + 1] = f2b(v[1]);
      T[r][c + 2] = f2b(v[2]); T[r][c + 3] = f2b(v[3]);
    }
    __syncthreads();
    const int cr = t >> 2;
    const int ck = (t & 3) * 16;
    bf16x8 u0, u1;
#pragma unroll
    for (int j = 0; j < 8; ++j) { u0[j] = T[ck + j][cr]; u1[j] = T[ck + 8 + j][cr]; }
    short* orow = Wt + (size_t)(mat * HID + c0 + cr) * HID + r0 + ck;
    *(bf16x8*)orow = u0;
    *(bf16x8*)(orow + 8) = u1;
  } else {
    // mask2 = mask * log2e (4096 floats)
#pragma unroll
    for (int i = 0; i < 4; ++i) {
      const int idx = (t * 4 + i * 1024);
      f32x4 v = *(const f32x4*)(mask + idx);
      v *= LOG2E;
      *(f32x4*)(mask2 + idx) = v;
    }
  }
}

// ---------------------------------------------------------------------------
// Fused QKV GEMM. Q,K written row-major [bh][s][64]; V written TRANSPOSED
// [bh][d][s] via LDS so attention can stage V^T with vector loads.
// Grid (18, 32), block 256 (4 waves), block tile 128x128, wave tile 64x64.
// ---------------------------------------------------------------------------
__global__ __launch_bounds__(256) void qkv_gemm(
    const short* __restrict__ Xb, const short* __restrict__ Wt,
    const float* __restrict__ bq, const float* __restrict__ bk,
    const float* __restrict__ bv,
    short* __restrict__ Qb, short* __restrict__ Kb, short* __restrict__ Vt)
{
  __shared__ __align__(16) short Tv[128][132];   // V transpose staging

  const int tid = threadIdx.x;
  const int w  = tid >> 6;
  const int l  = tid & 63;
  const int lr = l & 15;
  const int g  = l >> 4;
  const int wm = w >> 1;
  const int wn = w & 1;
  const int nb0 = blockIdx.x * 128;
  const int mb0 = blockIdx.y * 128;
  const int m0 = mb0 + wm * 64;
  const int n0 = nb0 + wn * 64;

  const short* __restrict__ Ap = Xb + (size_t)(m0 + lr) * HID + 8 * g;
  const short* __restrict__ Bp = Wt + (size_t)(n0 + lr) * HID + 8 * g;

  f32x4 acc[4][4];
#pragma unroll
  for (int mi = 0; mi < 4; ++mi)
#pragma unroll
    for (int ni = 0; ni < 4; ++ni) acc[mi][ni] = (f32x4){0.f, 0.f, 0.f, 0.f};

  for (int k = 0; k < HID; k += 32) {
    bf16x8 a[4], b[4];
#pragma unroll
    for (int i = 0; i < 4; ++i) {
      a[i] = *(const bf16x8*)(Ap + (size_t)(16 * i) * HID + k);
      b[i] = *(const bf16x8*)(Bp + (size_t)(16 * i) * HID + k);
    }
#pragma unroll
    for (int mi = 0; mi < 4; ++mi)
#pragma unroll
      for (int ni = 0; ni < 4; ++ni)
        acc[mi][ni] = __builtin_amdgcn_mfma_f32_16x16x32_bf16(a[mi], b[ni], acc[mi][ni], 0, 0, 0);
  }

  const int mat  = nb0 / HID;            // block-uniform: 0=Q 1=K 2=V
  const int colb = n0 - mat * HID;

  if (mat < 2) {
    const float* __restrict__ bias = (mat == 0) ? bq : bk;
    short* __restrict__ Out        = (mat == 0) ? Qb : Kb;
#pragma unroll
    for (int ni = 0; ni < 4; ++ni) {
      const int col = colb + 16 * ni + lr;
      const int h = col >> 6, d = col & 63;
      const float bias_v = bias[col];
#pragma unroll
      for (int mi = 0; mi < 4; ++mi) {
        const int mbase = m0 + 16 * mi + 4 * g;
#pragma unroll
        for (int r = 0; r < 4; ++r) {
          const int m = mbase + r;
          const int bb = m >> 11;
          const int s  = m & (SEQ - 1);
          Out[((size_t)(bb * NHEAD + h) * SEQ + s) * HD + d] = f2b(acc[mi][ni][r] + bias_v);
        }
      }
    }
  } else {
    // V: bias + bf16 into LDS transposed, then coalesced VT writes
#pragma unroll
    for (int ni = 0; ni < 4; ++ni) {
      const int col = colb + 16 * ni + lr;
      const float bias_v = bv[col];
      const int rowl = wn * 64 + 16 * ni + lr;       // n within block tile
#pragma unroll
      for (int mi = 0; mi < 4; ++mi) {
        bf16x4 pk;
#pragma unroll
        for (int r = 0; r < 4; ++r) pk[r] = f2b(acc[mi][ni][r] + bias_v);
        *(bf16x4*)&Tv[rowl][wm * 64 + 16 * mi + 4 * g] = pk;
      }
    }
    __syncthreads();
    const int row  = tid >> 1;           // n' 0..127
    const int half = tid & 1;            // m' half
    const int col  = nb0 - 2 * HID + row;
    const int h = col >> 6, d = col & 63;
    const int bb = mb0 >> 11;
    const int s0 = (mb0 & (SEQ - 1)) + half * 64;
    short* op = Vt + ((size_t)(bb * NHEAD + h) * HD + d) * SEQ + s0;
#pragma unroll
    for (int j = 0; j < 8; ++j)
      *(bf16x8*)(op + 8 * j) = *(const bf16x8*)&Tv[row][half * 64 + 8 * j];
  }
}

// ---------------------------------------------------------------------------
// Flash attention. Grid (32, 24), block 256 (4 waves), QBLK=16/wave, KVBLK=64.
// S^T = K*Q^T (lane-local q rows), exp2-domain online softmax with defer-max,
// P packed via v_cvt_pk_bf16_f32 through wave-private LDS, O^T += V^T*P^T.
// ---------------------------------------------------------------------------
__global__ __launch_bounds__(256) void attn_fwd(
    const short* __restrict__ Qb, const short* __restrict__ Kb,
    const short* __restrict__ Vt, const float* __restrict__ mask2,
    float* __restrict__ out)
{
  __shared__ __align__(16) short K_lds[64][72];     // [kv][d]
  __shared__ __align__(16) short VT_lds[64][72];    // [d][kv]
  __shared__ __align__(16) short P_lds[4][16][72];  // per-wave [q][kv]

  const int tid = threadIdx.x;
  const int w   = tid >> 6;
  const int l   = tid & 63;
  const int lr  = l & 15;
  const int g   = l >> 4;
  const int bh  = blockIdx.y;
  const int b   = bh / 12;
  const int q0  = blockIdx.x * 64 + w * 16;

  const short* __restrict__ Qh  = Qb + (size_t)bh * SEQ * HD;
  const short* __restrict__ Kh  = Kb + (size_t)bh * SEQ * HD;
  const short* __restrict__ Vth = Vt + (size_t)bh * HD * SEQ;   // [d][s]
  const float* __restrict__ mb2 = mask2 + (size_t)b * SEQ;

  const bf16x8 qf0 = *(const bf16x8*)(Qh + (size_t)(q0 + lr) * HD + 8 * g);
  const bf16x8 qf1 = *(const bf16x8*)(Qh + (size_t)(q0 + lr) * HD + 32 + 8 * g);

  f32x4 ot[4];
#pragma unroll
  for (int d0 = 0; d0 < 4; ++d0) ot[d0] = (f32x4){0.f, 0.f, 0.f, 0.f};
  float m2 = -INFINITY;   // running max, log2 domain
  float l_run = 0.f;

  const int sr = tid >> 2;            // staging row 0..63
  const int sc = (tid & 3) * 16;      // staging col (shorts)

  for (int kv0 = 0; kv0 < SEQ; kv0 += 64) {
    __syncthreads();
    // stage K [64 kv][64 d] and V^T [64 d][64 kv]: 2 b128 each per thread
    *(bf16x8*)&K_lds[sr][sc]      = *(const bf16x8*)(Kh + (size_t)(kv0 + sr) * HD + sc);
    *(bf16x8*)&K_lds[sr][sc + 8]  = *(const bf16x8*)(Kh + (size_t)(kv0 + sr) * HD + sc + 8);
    *(bf16x8*)&VT_lds[sr][sc]     = *(const bf16x8*)(Vth + (size_t)sr * SEQ + kv0 + sc);
    *(bf16x8*)&VT_lds[sr][sc + 8] = *(const bf16x8*)(Vth + (size_t)sr * SEQ + kv0 + sc + 8);
    __syncthreads();

    // S^T = K * Q^T : 4 kv-subtiles x (K-dim 64 = 2 chained MFMAs)
    f32x4 st[4];
    __builtin_amdgcn_s_setprio(1);
#pragma unroll
    for (int s = 0; s < 4; ++s) {
      bf16x8 ka0 = *(const bf16x8*)&K_lds[16 * s + lr][8 * g];
      bf16x8 ka1 = *(const bf16x8*)&K_lds[16 * s + lr][32 + 8 * g];
      f32x4 z = (f32x4){0.f, 0.f, 0.f, 0.f};
      z = __builtin_amdgcn_mfma_f32_16x16x32_bf16(ka0, qf0, z, 0, 0, 0);
      z = __builtin_amdgcn_mfma_f32_16x16x32_bf16(ka1, qf1, z, 0, 0, 0);
      st[s] = z;
    }
    __builtin_amdgcn_s_setprio(0);

    // scores in log2 domain; lane owns q=lr, kv = 16s + 4g + r
    float p[16];
    float tm = -INFINITY;
#pragma unroll
    for (int s = 0; s < 4; ++s) {
      f32x4 mv = *(const f32x4*)&mb2[kv0 + 16 * s + 4 * g];
#pragma unroll
      for (int r = 0; r < 4; ++r) {
        float sc2 = st[s][r] * C1 + mv[r];
        p[4 * s + r] = sc2;
        tm = fmaxf(tm, sc2);
      }
    }
    tm = fmaxf(tm, __shfl_xor(tm, 16, 64));
    tm = fmaxf(tm, __shfl_xor(tm, 32, 64));

    // defer-max: rescale only when max grew by > 8 (log2) for any row
    if (__any(tm > m2 + 8.f)) {
      const float mn = fmaxf(m2, tm);
      const float alpha = exp2f(m2 - mn);
#pragma unroll
      for (int d0 = 0; d0 < 4; ++d0) ot[d0] *= alpha;
      l_run *= alpha;
      m2 = mn;
    }

    float ts = 0.f;
#pragma unroll
    for (int i = 0; i < 16; ++i) { p[i] = exp2f(p[i] - m2); ts += p[i]; }
    ts += __shfl_xor(ts, 16, 64);
    ts += __shfl_xor(ts, 32, 64);
    l_run += ts;

    // pack P -> bf16 (cvt_pk) -> wave-private LDS (no block barrier needed)
#pragma unroll
    for (int s = 0; s < 4; ++s) {
      unsigned int u0, u1;
      asm("v_cvt_pk_bf16_f32 %0, %1, %2" : "=v"(u0) : "v"(p[4 * s]), "v"(p[4 * s + 1]));
      asm("v_cvt_pk_bf16_f32 %0, %1, %2" : "=v"(u1) : "v"(p[4 * s + 2]), "v"(p[4 * s + 3]));
      uint2 uv; uv.x = u0; uv.y = u1;
      *(uint2*)&P_lds[w][lr][16 * s + 4 * g] = uv;
    }

    const bf16x8 pb0 = *(const bf16x8*)&P_lds[w][lr][8 * g];
    const bf16x8 pb1 = *(const bf16x8*)&P_lds[w][lr][32 + 8 * g];

    // O^T += V^T * P^T : 4 d-subtiles x 2 chained MFMAs
    __builtin_amdgcn_s_setprio(1);
#pragma unroll
    for (int d0 = 0; d0 < 4; ++d0) {
      bf16x8 va0 = *(const bf16x8*)&VT_lds[16 * d0 + lr][8 * g];
      bf16x8 va1 = *(const bf16x8*)&VT_lds[16 * d0 + lr][32 + 8 * g];
      ot[d0] = __builtin_amdgcn_mfma_f32_16x16x32_bf16(va0, pb0, ot[d0], 0, 0, 0);
      ot[d0] = __builtin_amdgcn_mfma_f32_16x16x32_bf16(va1, pb1, ot[d0], 0, 0, 0);
    }
    __builtin_amdgcn_s_setprio(0);
  }

  const float inv = 1.f / l_run;
  const int h = bh - b * 12;
  float* ob = out + (size_t)(b * SEQ + q0 + lr) * HID + h * HD;
#pragma unroll
  for (int d0 = 0; d0 < 4; ++d0) {
    f32x4 o = ot[d0] * inv;
    *(f32x4*)&ob[16 * d0 + 4 * g] = o;
  }
}

// ---------------------------------------------------------------------------
extern "C" void kernel_launch(void* const* d_in, const int* in_sizes, int n_in,
                              void* d_out, int out_size, void* d_ws, size_t ws_size,
                              hipStream_t stream) {
  const float* X    = (const float*)d_in[0];
  const float* mask = (const float*)d_in[1];
  const float* Wq   = (const float*)d_in[2];
  const float* bq   = (const float*)d_in[3];
  const float* Wk   = (const float*)d_in[4];
  const float* bk   = (const float*)d_in[5];
  const float* Wv   = (const float*)d_in[6];
  const float* bv   = (const float*)d_in[7];
  float* out = (float*)d_out;

  short* Qb = (short*)d_ws;
  short* Kb = Qb + PH;
  short* Vt = Kb + PH;                 // V stored transposed [bh][d][s]
  short* Xb = Vt + PH;
  short* Wt = Xb + XEL;                // [2304][768] bf16
  float* mask2 = (float*)(Wt + (size_t)3 * HID * HID);

  prep<<<dim3(1201), 256, 0, stream>>>(X, Wq, Wk, Wv, mask, Xb, Wt, mask2);
  qkv_gemm<<<dim3(18, 32), 256, 0, stream>>>(Xb, Wt, bq, bk, bv, Qb, Kb, Vt);
  attn_fwd<<<dim3(32, 24), 256, 0, stream>>>(Qb, Kb, Vt, mask2, out);
}

// Round 6
// 148.310 us; speedup vs baseline: 1.9894x; 1.0144x over previous
//
#include <hip/hip_runtime.h>

#define HID 768
#define NHEAD 12
#define HD 64
#define SEQ 2048
#define BATCH 2
#define PH (BATCH * NHEAD * SEQ * HD)   // 3,145,728 elements per Q/K/V plane
#define XEL (BATCH * SEQ * HID)
#define LOG2E 1.4426950408889634f
#define C1 (0.125f * LOG2E)             // QK scale folded with log2e

typedef __attribute__((ext_vector_type(8))) short bf16x8;
typedef __attribute__((ext_vector_type(4))) short bf16x4;
typedef __attribute__((ext_vector_type(4))) float f32x4;

static __device__ __forceinline__ short f2b(float f) {
  unsigned int u = __builtin_bit_cast(unsigned int, f);
  unsigned int r = (u + 0x7fffu + ((u >> 16) & 1u)) >> 16;
  return (short)(unsigned short)r;
}

// ---------------------------------------------------------------------------
// Prep: [0,768)     : X f32 -> Xb bf16
//       [768,1200)  : W transpose+convert -> Wt[n][k] bf16
//       1200        : mask2 = mask * log2e
// ---------------------------------------------------------------------------
__global__ __launch_bounds__(256) void prep(
    const float* __restrict__ X,
    const float* __restrict__ Wq, const float* __restrict__ Wk,
    const float* __restrict__ Wv, const float* __restrict__ mask,
    short* __restrict__ Xb, short* __restrict__ Wt, float* __restrict__ mask2)
{
  __shared__ short T[64][65];
  const int t = threadIdx.x;
  const int blk = blockIdx.x;
  if (blk < 768) {
    const size_t base = (size_t)blk * 4096 + t * 16;
    f32x4 a0 = *(const f32x4*)(X + base);
    f32x4 a1 = *(const f32x4*)(X + base + 4);
    f32x4 a2 = *(const f32x4*)(X + base + 8);
    f32x4 a3 = *(const f32x4*)(X + base + 12);
    bf16x8 o0, o1;
#pragma unroll
    for (int i = 0; i < 4; ++i) {
      o0[i] = f2b(a0[i]); o0[4 + i] = f2b(a1[i]);
      o1[i] = f2b(a2[i]); o1[4 + i] = f2b(a3[i]);
    }
    *(bf16x8*)(Xb + base) = o0;
    *(bf16x8*)(Xb + base + 8) = o1;
  } else if (blk < 1200) {
    const int wb   = blk - 768;
    const int mat  = wb / 144;
    const int tile = wb - mat * 144;
    const int r0 = (tile / 12) * 64;
    const int c0 = (tile % 12) * 64;
    const float* __restrict__ W = (mat == 0) ? Wq : (mat == 1 ? Wk : Wv);
#pragma unroll
    for (int i = 0; i < 4; ++i) {
      const int r = (t >> 4) + 16 * i;
      const int c = (t & 15) * 4;
      f32x4 v = *(const f32x4*)(W + (size_t)(r0 + r) * HID + c0 + c);
      T[r][c + 0] = f2b(v[0]); T[r][c + 1] = f2b(v[1]);
      T[r][c + 2] = f2b(v[2]); T[r][c + 3] = f2b(v[3]);
    }
    __syncthreads();
    const int cr = t >> 2;
    const int ck = (t & 3) * 16;
    bf16x8 u0, u1;
#pragma unroll
    for (int j = 0; j < 8; ++j) { u0[j] = T[ck + j][cr]; u1[j] = T[ck + 8 + j][cr]; }
    short* orow = Wt + (size_t)(mat * HID + c0 + cr) * HID + r0 + ck;
    *(bf16x8*)orow = u0;
    *(bf16x8*)(orow + 8) = u1;
  } else {
#pragma unroll
    for (int i = 0; i < 4; ++i) {
      const int idx = (t * 4 + i * 1024);
      f32x4 v = *(const f32x4*)(mask + idx);
      v *= LOG2E;
      *(f32x4*)(mask2 + idx) = v;
    }
  }
}

// ---------------------------------------------------------------------------
// Fused QKV GEMM (unchanged from round 5 — verified). V written transposed.
// ---------------------------------------------------------------------------
__global__ __launch_bounds__(256) void qkv_gemm(
    const short* __restrict__ Xb, const short* __restrict__ Wt,
    const float* __restrict__ bq, const float* __restrict__ bk,
    const float* __restrict__ bv,
    short* __restrict__ Qb, short* __restrict__ Kb, short* __restrict__ Vt)
{
  __shared__ __align__(16) short Tv[128][132];

  const int tid = threadIdx.x;
  const int w  = tid >> 6;
  const int l  = tid & 63;
  const int lr = l & 15;
  const int g  = l >> 4;
  const int wm = w >> 1;
  const int wn = w & 1;
  const int nb0 = blockIdx.x * 128;
  const int mb0 = blockIdx.y * 128;
  const int m0 = mb0 + wm * 64;
  const int n0 = nb0 + wn * 64;

  const short* __restrict__ Ap = Xb + (size_t)(m0 + lr) * HID + 8 * g;
  const short* __restrict__ Bp = Wt + (size_t)(n0 + lr) * HID + 8 * g;

  f32x4 acc[4][4];
#pragma unroll
  for (int mi = 0; mi < 4; ++mi)
#pragma unroll
    for (int ni = 0; ni < 4; ++ni) acc[mi][ni] = (f32x4){0.f, 0.f, 0.f, 0.f};

  for (int k = 0; k < HID; k += 32) {
    bf16x8 a[4], b[4];
#pragma unroll
    for (int i = 0; i < 4; ++i) {
      a[i] = *(const bf16x8*)(Ap + (size_t)(16 * i) * HID + k);
      b[i] = *(const bf16x8*)(Bp + (size_t)(16 * i) * HID + k);
    }
#pragma unroll
    for (int mi = 0; mi < 4; ++mi)
#pragma unroll
      for (int ni = 0; ni < 4; ++ni)
        acc[mi][ni] = __builtin_amdgcn_mfma_f32_16x16x32_bf16(a[mi], b[ni], acc[mi][ni], 0, 0, 0);
  }

  const int mat  = nb0 / HID;
  const int colb = n0 - mat * HID;

  if (mat < 2) {
    const float* __restrict__ bias = (mat == 0) ? bq : bk;
    short* __restrict__ Out        = (mat == 0) ? Qb : Kb;
#pragma unroll
    for (int ni = 0; ni < 4; ++ni) {
      const int col = colb + 16 * ni + lr;
      const int h = col >> 6, d = col & 63;
      const float bias_v = bias[col];
#pragma unroll
      for (int mi = 0; mi < 4; ++mi) {
        const int mbase = m0 + 16 * mi + 4 * g;
#pragma unroll
        for (int r = 0; r < 4; ++r) {
          const int m = mbase + r;
          const int bb = m >> 11;
          const int s  = m & (SEQ - 1);
          Out[((size_t)(bb * NHEAD + h) * SEQ + s) * HD + d] = f2b(acc[mi][ni][r] + bias_v);
        }
      }
    }
  } else {
#pragma unroll
    for (int ni = 0; ni < 4; ++ni) {
      const int col = colb + 16 * ni + lr;
      const float bias_v = bv[col];
      const int rowl = wn * 64 + 16 * ni + lr;
#pragma unroll
      for (int mi = 0; mi < 4; ++mi) {
        bf16x4 pk;
#pragma unroll
        for (int r = 0; r < 4; ++r) pk[r] = f2b(acc[mi][ni][r] + bias_v);
        *(bf16x4*)&Tv[rowl][wm * 64 + 16 * mi + 4 * g] = pk;
      }
    }
    __syncthreads();
    const int row  = tid >> 1;
    const int half = tid & 1;
    const int col  = nb0 - 2 * HID + row;
    const int h = col >> 6, d = col & 63;
    const int bb = mb0 >> 11;
    const int s0 = (mb0 & (SEQ - 1)) + half * 64;
    short* op = Vt + ((size_t)(bb * NHEAD + h) * HD + d) * SEQ + s0;
#pragma unroll
    for (int j = 0; j < 8; ++j)
      *(bf16x8*)(op + 8 * j) = *(const bf16x8*)&Tv[row][half * 64 + 8 * j];
  }
}

// ---------------------------------------------------------------------------
// Flash attention, pipelined: double-buffered K/VT LDS, async-STAGE split
// (issue loads early / ds_write late), ONE barrier per 64-kv tile.
// ---------------------------------------------------------------------------
__global__ __launch_bounds__(256) void attn_fwd(
    const short* __restrict__ Qb, const short* __restrict__ Kb,
    const short* __restrict__ Vt, const float* __restrict__ mask2,
    float* __restrict__ out)
{
  __shared__ __align__(16) short K_lds[2][64][72];
  __shared__ __align__(16) short VT_lds[2][64][72];
  __shared__ __align__(16) short P_lds[4][16][72];

  const int tid = threadIdx.x;
  const int w   = tid >> 6;
  const int l   = tid & 63;
  const int lr  = l & 15;
  const int g   = l >> 4;
  const int bh  = blockIdx.y;
  const int b   = bh / 12;
  const int q0  = blockIdx.x * 64 + w * 16;

  const short* __restrict__ Qh  = Qb + (size_t)bh * SEQ * HD;
  const short* __restrict__ Kh  = Kb + (size_t)bh * SEQ * HD;
  const short* __restrict__ Vth = Vt + (size_t)bh * HD * SEQ;
  const float* __restrict__ mb2 = mask2 + (size_t)b * SEQ;

  const bf16x8 qf0 = *(const bf16x8*)(Qh + (size_t)(q0 + lr) * HD + 8 * g);
  const bf16x8 qf1 = *(const bf16x8*)(Qh + (size_t)(q0 + lr) * HD + 32 + 8 * g);

  f32x4 ot[4];
#pragma unroll
  for (int d0 = 0; d0 < 4; ++d0) ot[d0] = (f32x4){0.f, 0.f, 0.f, 0.f};
  float m2 = -INFINITY;
  float l_run = 0.f;

  const int sr = tid >> 2;            // staging row 0..63
  const int sc = (tid & 3) * 16;      // staging col (shorts)
  const short* __restrict__ Kp = Kh + (size_t)sr * HD + sc;
  const short* __restrict__ Vp = Vth + (size_t)sr * SEQ + sc;

  // prologue: stage tile 0 into buffer 0
  bf16x8 k0 = *(const bf16x8*)(Kp);
  bf16x8 k1 = *(const bf16x8*)(Kp + 8);
  bf16x8 v0 = *(const bf16x8*)(Vp);
  bf16x8 v1 = *(const bf16x8*)(Vp + 8);
  *(bf16x8*)&K_lds[0][sr][sc]      = k0;
  *(bf16x8*)&K_lds[0][sr][sc + 8]  = k1;
  *(bf16x8*)&VT_lds[0][sr][sc]     = v0;
  *(bf16x8*)&VT_lds[0][sr][sc + 8] = v1;

  for (int t = 0; t < SEQ / 64; ++t) {
    const int cur = t & 1;
    const int kv0 = t * 64;
    __syncthreads();   // staged writes of buf[cur] (from t-1 body) now visible

    // async-STAGE: issue next tile's global loads NOW (wrap at end, harmless)
    const size_t kvn = (size_t)(((t + 1) & (SEQ / 64 - 1)) * 64);
    k0 = *(const bf16x8*)(Kp + kvn * HD);
    k1 = *(const bf16x8*)(Kp + kvn * HD + 8);
    v0 = *(const bf16x8*)(Vp + kvn);
    v1 = *(const bf16x8*)(Vp + kvn + 8);

    // S^T = K * Q^T : 4 kv-subtiles x (K-dim 64 = 2 chained MFMAs)
    f32x4 st[4];
    __builtin_amdgcn_s_setprio(1);
#pragma unroll
    for (int s = 0; s < 4; ++s) {
      bf16x8 ka0 = *(const bf16x8*)&K_lds[cur][16 * s + lr][8 * g];
      bf16x8 ka1 = *(const bf16x8*)&K_lds[cur][16 * s + lr][32 + 8 * g];
      f32x4 z = (f32x4){0.f, 0.f, 0.f, 0.f};
      z = __builtin_amdgcn_mfma_f32_16x16x32_bf16(ka0, qf0, z, 0, 0, 0);
      z = __builtin_amdgcn_mfma_f32_16x16x32_bf16(ka1, qf1, z, 0, 0, 0);
      st[s] = z;
    }
    __builtin_amdgcn_s_setprio(0);

    // scores in log2 domain; lane owns q=lr, kv = 16s + 4g + r
    float p[16];
#pragma unroll
    for (int s = 0; s < 4; ++s) {
      f32x4 mv = *(const f32x4*)&mb2[kv0 + 16 * s + 4 * g];
#pragma unroll
      for (int r = 0; r < 4; ++r) p[4 * s + r] = st[s][r] * C1 + mv[r];
    }
    // tree max reduce (depth 4) + cross-lane
    float x0 = fmaxf(p[0], p[1]),  x1 = fmaxf(p[2], p[3]);
    float x2 = fmaxf(p[4], p[5]),  x3 = fmaxf(p[6], p[7]);
    float x4 = fmaxf(p[8], p[9]),  x5 = fmaxf(p[10], p[11]);
    float x6 = fmaxf(p[12], p[13]), x7 = fmaxf(p[14], p[15]);
    x0 = fmaxf(x0, x1); x2 = fmaxf(x2, x3); x4 = fmaxf(x4, x5); x6 = fmaxf(x6, x7);
    float tm = fmaxf(fmaxf(x0, x2), fmaxf(x4, x6));
    tm = fmaxf(tm, __shfl_xor(tm, 16, 64));
    tm = fmaxf(tm, __shfl_xor(tm, 32, 64));

    // defer-max: rescale only when max grew by > 8 (log2 domain)
    if (__any(tm > m2 + 8.f)) {
      const float mn = fmaxf(m2, tm);
      const float alpha = exp2f(m2 - mn);
#pragma unroll
      for (int d0 = 0; d0 < 4; ++d0) ot[d0] *= alpha;
      l_run *= alpha;
      m2 = mn;
    }

#pragma unroll
    for (int i = 0; i < 16; ++i) p[i] = exp2f(p[i] - m2);
    // tree sum
    float s0 = (p[0] + p[1]) + (p[2] + p[3]);
    float s1 = (p[4] + p[5]) + (p[6] + p[7]);
    float s2 = (p[8] + p[9]) + (p[10] + p[11]);
    float s3 = (p[12] + p[13]) + (p[14] + p[15]);
    float ts = (s0 + s1) + (s2 + s3);
    ts += __shfl_xor(ts, 16, 64);
    ts += __shfl_xor(ts, 32, 64);
    l_run += ts;

    // pack P -> bf16 -> wave-private LDS (no block barrier needed)
#pragma unroll
    for (int s = 0; s < 4; ++s) {
      unsigned int u0, u1;
      asm("v_cvt_pk_bf16_f32 %0, %1, %2" : "=v"(u0) : "v"(p[4 * s]), "v"(p[4 * s + 1]));
      asm("v_cvt_pk_bf16_f32 %0, %1, %2" : "=v"(u1) : "v"(p[4 * s + 2]), "v"(p[4 * s + 3]));
      uint2 uv; uv.x = u0; uv.y = u1;
      *(uint2*)&P_lds[w][lr][16 * s + 4 * g] = uv;
    }

    const bf16x8 pb0 = *(const bf16x8*)&P_lds[w][lr][8 * g];
    const bf16x8 pb1 = *(const bf16x8*)&P_lds[w][lr][32 + 8 * g];

    // O^T += V^T * P^T
    __builtin_amdgcn_s_setprio(1);
#pragma unroll
    for (int d0 = 0; d0 < 4; ++d0) {
      bf16x8 va0 = *(const bf16x8*)&VT_lds[cur][16 * d0 + lr][8 * g];
      bf16x8 va1 = *(const bf16x8*)&VT_lds[cur][16 * d0 + lr][32 + 8 * g];
      ot[d0] = __builtin_amdgcn_mfma_f32_16x16x32_bf16(va0, pb0, ot[d0], 0, 0, 0);
      ot[d0] = __builtin_amdgcn_mfma_f32_16x16x32_bf16(va1, pb1, ot[d0], 0, 0, 0);
    }
    __builtin_amdgcn_s_setprio(0);

    // write prefetched tile t+1 into the other buffer (safe: everyone past
    // this tile's barrier has finished reading buf[cur^1] in tile t-1)
    *(bf16x8*)&K_lds[cur ^ 1][sr][sc]      = k0;
    *(bf16x8*)&K_lds[cur ^ 1][sr][sc + 8]  = k1;
    *(bf16x8*)&VT_lds[cur ^ 1][sr][sc]     = v0;
    *(bf16x8*)&VT_lds[cur ^ 1][sr][sc + 8] = v1;
  }

  const float inv = 1.f / l_run;
  const int h = bh - b * 12;
  float* ob = out + (size_t)(b * SEQ + q0 + lr) * HID + h * HD;
#pragma unroll
  for (int d0 = 0; d0 < 4; ++d0) {
    f32x4 o = ot[d0] * inv;
    *(f32x4*)&ob[16 * d0 + 4 * g] = o;
  }
}

// ---------------------------------------------------------------------------
extern "C" void kernel_launch(void* const* d_in, const int* in_sizes, int n_in,
                              void* d_out, int out_size, void* d_ws, size_t ws_size,
                              hipStream_t stream) {
  const float* X    = (const float*)d_in[0];
  const float* mask = (const float*)d_in[1];
  const float* Wq   = (const float*)d_in[2];
  const float* bq   = (const float*)d_in[3];
  const float* Wk   = (const float*)d_in[4];
  const float* bk   = (const float*)d_in[5];
  const float* Wv   = (const float*)d_in[6];
  const float* bv   = (const float*)d_in[7];
  float* out = (float*)d_out;

  short* Qb = (short*)d_ws;
  short* Kb = Qb + PH;
  short* Vt = Kb + PH;                 // V stored transposed [bh][d][s]
  short* Xb = Vt + PH;
  short* Wt = Xb + XEL;
  float* mask2 = (float*)(Wt + (size_t)3 * HID * HID);

  prep<<<dim3(1201), 256, 0, stream>>>(X, Wq, Wk, Wv, mask, Xb, Wt, mask2);
  qkv_gemm<<<dim3(18, 32), 256, 0, stream>>>(Xb, Wt, bq, bk, bv, Qb, Kb, Vt);
  attn_fwd<<<dim3(32, 24), 256, 0, stream>>>(Qb, Kb, Vt, mask2, out);
}

// Round 7
// 95.520 us; speedup vs baseline: 3.0889x; 1.5527x over previous
//
#include <hip/hip_runtime.h>

#define HID 768
#define NHEAD 12
#define HD 64
#define SEQ 2048
#define BATCH 2
#define PH (BATCH * NHEAD * SEQ * HD)   // 3,145,728 elements per Q/K/V plane
#define XEL (BATCH * SEQ * HID)
#define LOG2E 1.4426950408889634f
#define C1 (0.125f * LOG2E)             // QK scale folded with log2e

typedef __attribute__((ext_vector_type(8))) short bf16x8;
typedef __attribute__((ext_vector_type(4))) short bf16x4;
typedef __attribute__((ext_vector_type(4))) float f32x4;

static __device__ __forceinline__ short f2b(float f) {
  unsigned int u = __builtin_bit_cast(unsigned int, f);
  unsigned int r = (u + 0x7fffu + ((u >> 16) & 1u)) >> 16;
  return (short)(unsigned short)r;
}

// ---------------------------------------------------------------------------
// Prep (unchanged): X->bf16, W transpose->Wt[n][k] bf16, mask*log2e
// ---------------------------------------------------------------------------
__global__ __launch_bounds__(256) void prep(
    const float* __restrict__ X,
    const float* __restrict__ Wq, const float* __restrict__ Wk,
    const float* __restrict__ Wv, const float* __restrict__ mask,
    short* __restrict__ Xb, short* __restrict__ Wt, float* __restrict__ mask2)
{
  __shared__ short T[64][65];
  const int t = threadIdx.x;
  const int blk = blockIdx.x;
  if (blk < 768) {
    const size_t base = (size_t)blk * 4096 + t * 16;
    f32x4 a0 = *(const f32x4*)(X + base);
    f32x4 a1 = *(const f32x4*)(X + base + 4);
    f32x4 a2 = *(const f32x4*)(X + base + 8);
    f32x4 a3 = *(const f32x4*)(X + base + 12);
    bf16x8 o0, o1;
#pragma unroll
    for (int i = 0; i < 4; ++i) {
      o0[i] = f2b(a0[i]); o0[4 + i] = f2b(a1[i]);
      o1[i] = f2b(a2[i]); o1[4 + i] = f2b(a3[i]);
    }
    *(bf16x8*)(Xb + base) = o0;
    *(bf16x8*)(Xb + base + 8) = o1;
  } else if (blk < 1200) {
    const int wb   = blk - 768;
    const int mat  = wb / 144;
    const int tile = wb - mat * 144;
    const int r0 = (tile / 12) * 64;
    const int c0 = (tile % 12) * 64;
    const float* __restrict__ W = (mat == 0) ? Wq : (mat == 1 ? Wk : Wv);
#pragma unroll
    for (int i = 0; i < 4; ++i) {
      const int r = (t >> 4) + 16 * i;
      const int c = (t & 15) * 4;
      f32x4 v = *(const f32x4*)(W + (size_t)(r0 + r) * HID + c0 + c);
      T[r][c + 0] = f2b(v[0]); T[r][c + 1] = f2b(v[1]);
      T[r][c + 2] = f2b(v[2]); T[r][c + 3] = f2b(v[3]);
    }
    __syncthreads();
    const int cr = t >> 2;
    const int ck = (t & 3) * 16;
    bf16x8 u0, u1;
#pragma unroll
    for (int j = 0; j < 8; ++j) { u0[j] = T[ck + j][cr]; u1[j] = T[ck + 8 + j][cr]; }
    short* orow = Wt + (size_t)(mat * HID + c0 + cr) * HID + r0 + ck;
    *(bf16x8*)orow = u0;
    *(bf16x8*)(orow + 8) = u1;
  } else {
#pragma unroll
    for (int i = 0; i < 4; ++i) {
      const int idx = (t * 4 + i * 1024);
      f32x4 v = *(const f32x4*)(mask + idx);
      v *= LOG2E;
      *(f32x4*)(mask2 + idx) = v;
    }
  }
}

// ---------------------------------------------------------------------------
// Fused QKV GEMM, m97-style: BK=64 LDS staging via global_load_lds width 16,
// XOR slot-swizzle (slot ^= row&7) with inverse-swizzled global source,
// 2 barriers per K-step, XCD-chunked block swizzle. V written transposed.
// Grid 576x1, block 256 (4 waves). Block tile 128x128, wave tile 64x64.
// ---------------------------------------------------------------------------
__global__ __launch_bounds__(256, 3) void qkv_gemm(
    const short* __restrict__ Xb, const short* __restrict__ Wt,
    const float* __restrict__ bq, const float* __restrict__ bk,
    const float* __restrict__ bv,
    short* __restrict__ Qb, short* __restrict__ Kb, short* __restrict__ Vt)
{
  // 33792 B shared: staging A[128][64]+B[128][64] (32 KB), aliased with Tv[128][132]
  __shared__ __align__(16) short SM[128 * 132];
  short (*A_lds)[64] = (short(*)[64])SM;
  short (*B_lds)[64] = (short(*)[64])(SM + 128 * 64);
  short (*Tv)[132]   = (short(*)[132])SM;

  const int tid = threadIdx.x;
  const int w  = tid >> 6;
  const int l  = tid & 63;
  const int lr = l & 15;
  const int g  = l >> 4;
  const int wm = w >> 1;
  const int wn = w & 1;

  // XCD-chunked bijective swizzle: 576 = 8 XCDs x 72 tiles
  const int raw = blockIdx.x;
  const int swz = (raw & 7) * 72 + (raw >> 3);
  const int by  = swz / 18;
  const int bx  = swz - by * 18;
  const int mb0 = by * 128;
  const int nb0 = bx * 128;

  // staging lane geometry: 1KB/instr = 8 rows x 128B; lane l -> row+(l>>3),
  // phys slot (l&7); global col slot = (l&7) ^ (l>>3)  (inverse swizzle)
  const int lrow8 = l >> 3;
  const int lslot = (l & 7) ^ lrow8;
  const short* __restrict__ pA = Xb + (size_t)(mb0 + w * 32 + lrow8) * HID + lslot * 8;
  const short* __restrict__ pB = Wt + (size_t)(nb0 + w * 32 + lrow8) * HID + lslot * 8;

  f32x4 acc[4][4];
#pragma unroll
  for (int mi = 0; mi < 4; ++mi)
#pragma unroll
    for (int ni = 0; ni < 4; ++ni) acc[mi][ni] = (f32x4){0.f, 0.f, 0.f, 0.f};

  const int rsw = (lr & 7) << 3;   // read-side swizzle: (slot ^ (row&7))*8

  for (int ks = 0; ks < HID / 64; ++ks) {
    const int k0 = ks * 64;
    __syncthreads();   // previous K-step's reads of the buffer are done
#pragma unroll
    for (int i = 0; i < 4; ++i) {
      __builtin_amdgcn_global_load_lds(
          (const void*)(pA + k0 + i * 8 * HID), (void*)&A_lds[w * 32 + i * 8][0], 16, 0, 0);
      __builtin_amdgcn_global_load_lds(
          (const void*)(pB + k0 + i * 8 * HID), (void*)&B_lds[w * 32 + i * 8][0], 16, 0, 0);
    }
    __syncthreads();   // vmcnt drained by compiler before s_barrier

#pragma unroll
    for (int h = 0; h < 2; ++h) {
      bf16x8 a[4], b[4];
#pragma unroll
      for (int i = 0; i < 4; ++i) {
        const int coff = (((h << 2) | g) << 3) ^ rsw;   // swizzled 16B slot
        a[i] = *(const bf16x8*)&A_lds[wm * 64 + 16 * i + lr][coff];
        b[i] = *(const bf16x8*)&B_lds[wn * 64 + 16 * i + lr][coff];
      }
#pragma unroll
      for (int mi = 0; mi < 4; ++mi)
#pragma unroll
        for (int ni = 0; ni < 4; ++ni)
          acc[mi][ni] = __builtin_amdgcn_mfma_f32_16x16x32_bf16(a[mi], b[ni], acc[mi][ni], 0, 0, 0);
    }
  }

  const int mat  = nb0 / HID;              // block-uniform: 0=Q 1=K 2=V
  const int n0   = nb0 + wn * 64;
  const int m0   = mb0 + wm * 64;
  const int colb = n0 - mat * HID;

  if (mat < 2) {
    const float* __restrict__ bias = (mat == 0) ? bq : bk;
    short* __restrict__ Out        = (mat == 0) ? Qb : Kb;
#pragma unroll
    for (int ni = 0; ni < 4; ++ni) {
      const int col = colb + 16 * ni + lr;
      const int h = col >> 6, d = col & 63;
      const float bias_v = bias[col];
#pragma unroll
      for (int mi = 0; mi < 4; ++mi) {
        const int mbase = m0 + 16 * mi + 4 * g;
#pragma unroll
        for (int r = 0; r < 4; ++r) {
          const int m = mbase + r;
          const int bb = m >> 11;
          const int s  = m & (SEQ - 1);
          Out[((size_t)(bb * NHEAD + h) * SEQ + s) * HD + d] = f2b(acc[mi][ni][r] + bias_v);
        }
      }
    }
  } else {
    __syncthreads();   // all waves done reading staging LDS before Tv reuse
#pragma unroll
    for (int ni = 0; ni < 4; ++ni) {
      const int col = colb + 16 * ni + lr;
      const float bias_v = bv[col];
      const int rowl = wn * 64 + 16 * ni + lr;
#pragma unroll
      for (int mi = 0; mi < 4; ++mi) {
        bf16x4 pk;
#pragma unroll
        for (int r = 0; r < 4; ++r) pk[r] = f2b(acc[mi][ni][r] + bias_v);
        *(bf16x4*)&Tv[rowl][wm * 64 + 16 * mi + 4 * g] = pk;
      }
    }
    __syncthreads();
    const int row  = tid >> 1;
    const int half = tid & 1;
    const int col  = nb0 - 2 * HID + row;
    const int h = col >> 6, d = col & 63;
    const int bb = mb0 >> 11;
    const int s0 = (mb0 & (SEQ - 1)) + half * 64;
    short* op = Vt + ((size_t)(bb * NHEAD + h) * HD + d) * SEQ + s0;
#pragma unroll
    for (int j = 0; j < 8; ++j)
      *(bf16x8*)(op + 8 * j) = *(const bf16x8*)&Tv[row][half * 64 + 8 * j];
  }
}

// ---------------------------------------------------------------------------
// Flash attention (byte-identical to round 6 — verified PASS).
// ---------------------------------------------------------------------------
__global__ __launch_bounds__(256) void attn_fwd(
    const short* __restrict__ Qb, const short* __restrict__ Kb,
    const short* __restrict__ Vt, const float* __restrict__ mask2,
    float* __restrict__ out)
{
  __shared__ __align__(16) short K_lds[2][64][72];
  __shared__ __align__(16) short VT_lds[2][64][72];
  __shared__ __align__(16) short P_lds[4][16][72];

  const int tid = threadIdx.x;
  const int w   = tid >> 6;
  const int l   = tid & 63;
  const int lr  = l & 15;
  const int g   = l >> 4;
  const int bh  = blockIdx.y;
  const int b   = bh / 12;
  const int q0  = blockIdx.x * 64 + w * 16;

  const short* __restrict__ Qh  = Qb + (size_t)bh * SEQ * HD;
  const short* __restrict__ Kh  = Kb + (size_t)bh * SEQ * HD;
  const short* __restrict__ Vth = Vt + (size_t)bh * HD * SEQ;
  const float* __restrict__ mb2 = mask2 + (size_t)b * SEQ;

  const bf16x8 qf0 = *(const bf16x8*)(Qh + (size_t)(q0 + lr) * HD + 8 * g);
  const bf16x8 qf1 = *(const bf16x8*)(Qh + (size_t)(q0 + lr) * HD + 32 + 8 * g);

  f32x4 ot[4];
#pragma unroll
  for (int d0 = 0; d0 < 4; ++d0) ot[d0] = (f32x4){0.f, 0.f, 0.f, 0.f};
  float m2 = -INFINITY;
  float l_run = 0.f;

  const int sr = tid >> 2;
  const int sc = (tid & 3) * 16;
  const short* __restrict__ Kp = Kh + (size_t)sr * HD + sc;
  const short* __restrict__ Vp = Vth + (size_t)sr * SEQ + sc;

  bf16x8 k0 = *(const bf16x8*)(Kp);
  bf16x8 k1 = *(const bf16x8*)(Kp + 8);
  bf16x8 v0 = *(const bf16x8*)(Vp);
  bf16x8 v1 = *(const bf16x8*)(Vp + 8);
  *(bf16x8*)&K_lds[0][sr][sc]      = k0;
  *(bf16x8*)&K_lds[0][sr][sc + 8]  = k1;
  *(bf16x8*)&VT_lds[0][sr][sc]     = v0;
  *(bf16x8*)&VT_lds[0][sr][sc + 8] = v1;

  for (int t = 0; t < SEQ / 64; ++t) {
    const int cur = t & 1;
    const int kv0 = t * 64;
    __syncthreads();

    const size_t kvn = (size_t)(((t + 1) & (SEQ / 64 - 1)) * 64);
    k0 = *(const bf16x8*)(Kp + kvn * HD);
    k1 = *(const bf16x8*)(Kp + kvn * HD + 8);
    v0 = *(const bf16x8*)(Vp + kvn);
    v1 = *(const bf16x8*)(Vp + kvn + 8);

    f32x4 st[4];
    __builtin_amdgcn_s_setprio(1);
#pragma unroll
    for (int s = 0; s < 4; ++s) {
      bf16x8 ka0 = *(const bf16x8*)&K_lds[cur][16 * s + lr][8 * g];
      bf16x8 ka1 = *(const bf16x8*)&K_lds[cur][16 * s + lr][32 + 8 * g];
      f32x4 z = (f32x4){0.f, 0.f, 0.f, 0.f};
      z = __builtin_amdgcn_mfma_f32_16x16x32_bf16(ka0, qf0, z, 0, 0, 0);
      z = __builtin_amdgcn_mfma_f32_16x16x32_bf16(ka1, qf1, z, 0, 0, 0);
      st[s] = z;
    }
    __builtin_amdgcn_s_setprio(0);

    float p[16];
#pragma unroll
    for (int s = 0; s < 4; ++s) {
      f32x4 mv = *(const f32x4*)&mb2[kv0 + 16 * s + 4 * g];
#pragma unroll
      for (int r = 0; r < 4; ++r) p[4 * s + r] = st[s][r] * C1 + mv[r];
    }
    float x0 = fmaxf(p[0], p[1]),  x1 = fmaxf(p[2], p[3]);
    float x2 = fmaxf(p[4], p[5]),  x3 = fmaxf(p[6], p[7]);
    float x4 = fmaxf(p[8], p[9]),  x5 = fmaxf(p[10], p[11]);
    float x6 = fmaxf(p[12], p[13]), x7 = fmaxf(p[14], p[15]);
    x0 = fmaxf(x0, x1); x2 = fmaxf(x2, x3); x4 = fmaxf(x4, x5); x6 = fmaxf(x6, x7);
    float tm = fmaxf(fmaxf(x0, x2), fmaxf(x4, x6));
    tm = fmaxf(tm, __shfl_xor(tm, 16, 64));
    tm = fmaxf(tm, __shfl_xor(tm, 32, 64));

    if (__any(tm > m2 + 8.f)) {
      const float mn = fmaxf(m2, tm);
      const float alpha = exp2f(m2 - mn);
#pragma unroll
      for (int d0 = 0; d0 < 4; ++d0) ot[d0] *= alpha;
      l_run *= alpha;
      m2 = mn;
    }

#pragma unroll
    for (int i = 0; i < 16; ++i) p[i] = exp2f(p[i] - m2);
    float s0 = (p[0] + p[1]) + (p[2] + p[3]);
    float s1 = (p[4] + p[5]) + (p[6] + p[7]);
    float s2 = (p[8] + p[9]) + (p[10] + p[11]);
    float s3 = (p[12] + p[13]) + (p[14] + p[15]);
    float ts = (s0 + s1) + (s2 + s3);
    ts += __shfl_xor(ts, 16, 64);
    ts += __shfl_xor(ts, 32, 64);
    l_run += ts;

#pragma unroll
    for (int s = 0; s < 4; ++s) {
      unsigned int u0, u1;
      asm("v_cvt_pk_bf16_f32 %0, %1, %2" : "=v"(u0) : "v"(p[4 * s]), "v"(p[4 * s + 1]));
      asm("v_cvt_pk_bf16_f32 %0, %1, %2" : "=v"(u1) : "v"(p[4 * s + 2]), "v"(p[4 * s + 3]));
      uint2 uv; uv.x = u0; uv.y = u1;
      *(uint2*)&P_lds[w][lr][16 * s + 4 * g] = uv;
    }

    const bf16x8 pb0 = *(const bf16x8*)&P_lds[w][lr][8 * g];
    const bf16x8 pb1 = *(const bf16x8*)&P_lds[w][lr][32 + 8 * g];

    __builtin_amdgcn_s_setprio(1);
#pragma unroll
    for (int d0 = 0; d0 < 4; ++d0) {
      bf16x8 va0 = *(const bf16x8*)&VT_lds[cur][16 * d0 + lr][8 * g];
      bf16x8 va1 = *(const bf16x8*)&VT_lds[cur][16 * d0 + lr][32 + 8 * g];
      ot[d0] = __builtin_amdgcn_mfma_f32_16x16x32_bf16(va0, pb0, ot[d0], 0, 0, 0);
      ot[d0] = __builtin_amdgcn_mfma_f32_16x16x32_bf16(va1, pb1, ot[d0], 0, 0, 0);
    }
    __builtin_amdgcn_s_setprio(0);

    *(bf16x8*)&K_lds[cur ^ 1][sr][sc]      = k0;
    *(bf16x8*)&K_lds[cur ^ 1][sr][sc + 8]  = k1;
    *(bf16x8*)&VT_lds[cur ^ 1][sr][sc]     = v0;
    *(bf16x8*)&VT_lds[cur ^ 1][sr][sc + 8] = v1;
  }

  const float inv = 1.f / l_run;
  const int h = bh - b * 12;
  float* ob = out + (size_t)(b * SEQ + q0 + lr) * HID + h * HD;
#pragma unroll
  for (int d0 = 0; d0 < 4; ++d0) {
    f32x4 o = ot[d0] * inv;
    *(f32x4*)&ob[16 * d0 + 4 * g] = o;
  }
}

// ---------------------------------------------------------------------------
extern "C" void kernel_launch(void* const* d_in, const int* in_sizes, int n_in,
                              void* d_out, int out_size, void* d_ws, size_t ws_size,
                              hipStream_t stream) {
  const float* X    = (const float*)d_in[0];
  const float* mask = (const float*)d_in[1];
  const float* Wq   = (const float*)d_in[2];
  const float* bq   = (const float*)d_in[3];
  const float* Wk   = (const float*)d_in[4];
  const float* bk   = (const float*)d_in[5];
  const float* Wv   = (const float*)d_in[6];
  const float* bv   = (const float*)d_in[7];
  float* out = (float*)d_out;

  short* Qb = (short*)d_ws;
  short* Kb = Qb + PH;
  short* Vt = Kb + PH;                 // V stored transposed [bh][d][s]
  short* Xb = Vt + PH;
  short* Wt = Xb + XEL;
  float* mask2 = (float*)(Wt + (size_t)3 * HID * HID);

  prep<<<dim3(1201), 256, 0, stream>>>(X, Wq, Wk, Wv, mask, Xb, Wt, mask2);
  qkv_gemm<<<dim3(576), 256, 0, stream>>>(Xb, Wt, bq, bk, bv, Qb, Kb, Vt);
  attn_fwd<<<dim3(32, 24), 256, 0, stream>>>(Qb, Kb, Vt, mask2, out);
}